// Round 1
// baseline (157.078 us; speedup 1.0000x reference)
//
#include <hip/hip_runtime.h>
#include <math.h>

// Problem constants (from reference):
// x:      [16, 8, 32, 32, 16] f32   (B, MIN, H, W, DIN)
// w:      [128, 128, 3, 3]    f32   (CIN, COUT, KH, KW)  torch ConvTranspose2d layout
// bias:   [128]               f32
// b_route unused: routing collapses to identity (Min axis of pred has size 1,
//                 softmax weights sum to 1) -> out = squash(deconv(x)+bias)
// out:    [16, 8, 64, 64, 16] f32
//
// ConvTranspose2d S=2,P=1,OP=1,K=3:
//   y[b,co,oh,ow] = bias[co] + sum_{kh,kw,ci} x[b,ci,ih,iw] * w[ci,co,kh,kw]
//   with ih=(oh+1-kh)/2 when integral & in [0,32), same for iw.
// Parity classes: oh even -> kh=1 ; oh odd -> kh in {0,2}; same for ow/kw.

__device__ __forceinline__ float4 ld4(const float* p) {
    return *(const float4*)p;
}

__device__ __forceinline__ void fma4(float4& a, float s, const float4& w) {
    a.x += s * w.x; a.y += s * w.y; a.z += s * w.z; a.w += s * w.w;
}

// PH = 0: even output rows (kh=1 only, 3 LDS planes = 24KB)
// PH = 1: odd  output rows (kh in {0,2}, 6 LDS planes = 48KB)
template <int PH>
__global__ __launch_bounds__(256) void deconv_squash_kernel(
    const float* __restrict__ x, const float* __restrict__ wgt,
    const float* __restrict__ bias, float* __restrict__ out)
{
    constexpr int NP = PH ? 6 : 3;
    __shared__ float ws[NP * 2048];  // ws[p][ci][d] : p*2048 + ci*16 + d

    const int tid = threadIdx.x;
    const int jb  = blockIdx.x;   // 0..3  (16-row band of this parity)
    const int m   = blockIdx.y;   // 0..7  (output capsule)
    const int b   = blockIdx.z;   // 0..15 (batch)

    // --- stage weights for this m, transposed to [plane][ci][d] ---
    // wgt flat index: ci*1152 + co*9 + kh*3 + kw, co = m*16 + d
    for (int idx = tid; idx < NP * 2048; idx += 256) {
        int p   = idx >> 11;
        int rem = idx & 2047;
        int ci  = rem >> 4;
        int d   = rem & 15;
        int kh, kw;
        if (PH) { kh = (p / 3) * 2; kw = p % 3; }
        else    { kh = 1;           kw = p;     }
        ws[idx] = wgt[ci * 1152 + (m * 16 + d) * 9 + kh * 3 + kw];
    }
    __syncthreads();

    // --- thread -> output coords (parity-pure waves) ---
    const int wv   = tid >> 6;     // wave 0..3
    const int lane = tid & 63;
    const int pw   = wv & 1;       // column parity of this wave (uniform)
    const int g    = wv >> 1;      // row group
    const int c    = lane & 31;    // column index within parity class
    const int rsel = lane >> 5;
    const int tb   = g * 4 + rsel * 2;          // t in {0,2,4,6}
    const int oh_a = 16 * jb + 2 * tb + PH;     // this thread's 2 rows
    const int oh_b = oh_a + 2;
    const int ow   = 2 * c + pw;

    // --- accumulators init with bias ---
    float4 acc0[4], acc1[4];
    #pragma unroll
    for (int q = 0; q < 4; ++q) {
        float4 bq = ld4(bias + m * 16 + q * 4);
        acc0[q] = bq; acc1[q] = bq;
    }

    const float* xb = x + b * 131072;  // x[b][mi][ih][iw][di]; strides 16384/512/16/1

    #pragma unroll
    for (int khi = 0; khi < (PH ? 2 : 1); ++khi) {
        const int kh   = PH ? khi * 2 : 1;
        const int ih_a = (oh_a + 1 - kh) >> 1;  // >= 0 always (checked analytically)
        const int ih_b = ih_a + 1;
        float mra = 1.f, mrb = 1.f;
        if (PH) {  // only oh=63,kh=0 can run off the end
            if (ih_a >= 32) mra = 0.f;
            if (ih_b >= 32) mrb = 0.f;
        }
        const int iha_c = min(ih_a, 31);
        const int ihb_c = min(ih_b, 31);

        #pragma unroll
        for (int kw = 0; kw < 3; ++kw) {
            if (((pw + 1 - kw) & 1) != 0) continue;  // wave-uniform skip
            const int iw = c + ((pw + 1 - kw) >> 1);
            const float mc = (iw < 32) ? 1.f : 0.f;  // ow=63,kw=0 edge
            const int iwc = min(iw, 31);
            const float ma = mra * mc, mb = mrb * mc;
            const int p = PH ? (khi * 3 + kw) : kw;

            const float* xra = xb + iha_c * 512 + iwc * 16;
            const float* xrb = xb + ihb_c * 512 + iwc * 16;
            const float* wp  = ws + p * 2048;

            for (int mi = 0; mi < 8; ++mi) {
                #pragma unroll
                for (int dq = 0; dq < 4; ++dq) {
                    float4 xa = ld4(xra + mi * 16384 + dq * 4);
                    float4 xv = ld4(xrb + mi * 16384 + dq * 4);
                    float av[4] = {xa.x * ma, xa.y * ma, xa.z * ma, xa.w * ma};
                    float bv[4] = {xv.x * mb, xv.y * mb, xv.z * mb, xv.w * mb};
                    #pragma unroll
                    for (int k = 0; k < 4; ++k) {
                        const int ci = mi * 16 + dq * 4 + k;
                        const float* wr = wp + ci * 16;
                        float4 w0 = ld4(wr);     float4 w1 = ld4(wr + 4);
                        float4 w2 = ld4(wr + 8); float4 w3 = ld4(wr + 12);
                        fma4(acc0[0], av[k], w0); fma4(acc0[1], av[k], w1);
                        fma4(acc0[2], av[k], w2); fma4(acc0[3], av[k], w3);
                        fma4(acc1[0], bv[k], w0); fma4(acc1[1], bv[k], w1);
                        fma4(acc1[2], bv[k], w2); fma4(acc1[3], bv[k], w3);
                    }
                }
            }
        }
    }

    // --- fused squash over d (16) + store ---
    float sq0 = 0.f, sq1 = 0.f;
    #pragma unroll
    for (int q = 0; q < 4; ++q) {
        sq0 += acc0[q].x * acc0[q].x + acc0[q].y * acc0[q].y
             + acc0[q].z * acc0[q].z + acc0[q].w * acc0[q].w;
        sq1 += acc1[q].x * acc1[q].x + acc1[q].y * acc1[q].y
             + acc1[q].z * acc1[q].z + acc1[q].w * acc1[q].w;
    }
    const float f0 = sq0 / ((1.f + sq0) * sqrtf(sq0 + 1e-7f));
    const float f1 = sq1 / ((1.f + sq1) * sqrtf(sq1 + 1e-7f));

    float* o0 = out + ((((b * 8 + m) * 64 + oh_a) * 64) + ow) * 16;
    float* o1 = out + ((((b * 8 + m) * 64 + oh_b) * 64) + ow) * 16;
    #pragma unroll
    for (int q = 0; q < 4; ++q) {
        float4 v0 = make_float4(acc0[q].x * f0, acc0[q].y * f0,
                                acc0[q].z * f0, acc0[q].w * f0);
        float4 v1 = make_float4(acc1[q].x * f1, acc1[q].y * f1,
                                acc1[q].z * f1, acc1[q].w * f1);
        *(float4*)(o0 + q * 4) = v0;
        *(float4*)(o1 + q * 4) = v1;
    }
}

extern "C" void kernel_launch(void* const* d_in, const int* in_sizes, int n_in,
                              void* d_out, int out_size, void* d_ws, size_t ws_size,
                              hipStream_t stream) {
    const float* x    = (const float*)d_in[0];
    const float* wgt  = (const float*)d_in[1];
    const float* bias = (const float*)d_in[2];
    // d_in[3] (b_route) mathematically unused: routing collapses to identity.
    float* out = (float*)d_out;

    dim3 grid(4, 8, 16);   // (row-band, m, b)
    dim3 block(256);
    deconv_squash_kernel<0><<<grid, block, 0, stream>>>(x, wgt, bias, out);
    deconv_squash_kernel<1><<<grid, block, 0, stream>>>(x, wgt, bias, out);
}

// Round 2
// 141.468 us; speedup vs baseline: 1.1103x; 1.1103x over previous
//
#include <hip/hip_runtime.h>
#include <hip/hip_bf16.h>
#include <math.h>

// out = squash(ConvTranspose2d(x) + bias); routing loop is identity (see R0/R1).
//
// MFMA formulation, per parity class (ph,pw):
//   out[px, co] = bias[co] + sum_{kh in Kh(ph), kw in Kw(pw)} sum_ci
//                 x[b, ci, ih, iw] * w[ci, co, kh, kw]
// GEMM: M = pixels, N = co (128), K = 128*taps. bf16 MFMA 16x16x32.
//
// ws layout: [0, 4MB)   x_bf16  [16][8][32][32][16]   (same strides as x)
//            [4MB, ...) Wt bf16 [9][128][128] = Wt[tap][co][ci]  (B^T layout)

typedef __attribute__((ext_vector_type(8))) __bf16 bf16x8;
typedef __attribute__((ext_vector_type(4))) float f32x4;

#define XBF_ELEMS (16 * 8 * 32 * 32 * 16)  // 2097152

__global__ __launch_bounds__(256) void convert_x(const float* __restrict__ x,
                                                 __hip_bfloat16* __restrict__ xb) {
    const int i = (blockIdx.x * 256 + threadIdx.x) * 8;
    float4 a = *(const float4*)(x + i);
    float4 b = *(const float4*)(x + i + 4);
    __hip_bfloat16 o[8];
    o[0] = __float2bfloat16(a.x); o[1] = __float2bfloat16(a.y);
    o[2] = __float2bfloat16(a.z); o[3] = __float2bfloat16(a.w);
    o[4] = __float2bfloat16(b.x); o[5] = __float2bfloat16(b.y);
    o[6] = __float2bfloat16(b.z); o[7] = __float2bfloat16(b.w);
    *(ulonglong2*)(xb + i) = *(const ulonglong2*)o;
}

__global__ __launch_bounds__(256) void transpose_w(const float* __restrict__ w,
                                                   __hip_bfloat16* __restrict__ wt) {
    // out idx = tap*16384 + co*128 + ci ; src = w[ci*1152 + co*9 + tap]
    const int idx = blockIdx.x * 256 + threadIdx.x;  // < 147456
    const int tap = idx >> 14;
    const int co  = (idx >> 7) & 127;
    const int ci  = idx & 127;
    wt[idx] = __float2bfloat16(w[ci * 1152 + co * 9 + tap]);
}

__global__ __launch_bounds__(256) void caps_mfma(
    const __hip_bfloat16* __restrict__ xb,   // [16][8][32][32][16] bf16
    const __hip_bfloat16* __restrict__ wt,   // [9][128][128] bf16 (tap, co, ci)
    const float* __restrict__ bias,          // [128]
    float* __restrict__ out)                 // [16][8][64][64][16] f32
{
    const int tid  = threadIdx.x;
    const int lane = tid & 63;
    const int wv   = tid >> 6;         // wave 0..3
    const int q    = blockIdx.x;       // 0..15 (class-row pair)
    const int pc   = blockIdx.y;       // 0..3 : ph = pc>>1, pw = pc&1
    const int b    = blockIdx.z;       // 0..15

    const int ph = pc >> 1, pw = pc & 1;
    const int rw = q * 2 + (wv >> 1);  // class row 0..31 (oh = 2*rw + ph)
    const int ch = wv & 1;             // column half (16 class-cols each)
    const int n16  = lane & 15;
    const int quad = lane >> 4;

    // A fragment: A[m = lane&15][k = quad*8 + j]; m -> pixel class-col c.
    const int c = ch * 16 + n16;
    // k -> ci = s*32 + quad*8 + j  =>  mi = 2s + (quad>>1), di0 = (quad&1)*8
    const int offq = (quad >> 1) * 16384 + (quad & 1) * 8;
    const __hip_bfloat16* xbase = xb + b * 131072;

    // B fragment: Bfrag[n = lane&15][k = quad*8 + j] = Wt[ntile*16+n][k]
    const int wlane = n16 * 128 + quad * 8;

    const int nh = ph ? 2 : 1;
    const int nw = pw ? 2 : 1;

    f32x4 acc[8];
    #pragma unroll
    for (int t = 0; t < 8; ++t) acc[t] = (f32x4){0.f, 0.f, 0.f, 0.f};
    const bf16x8 zf = {};

    for (int khi = 0; khi < nh; ++khi) {
        const int kh = ph ? khi * 2 : 1;
        const int dh = ph ? (1 - khi) : 0;   // ih = rw + dh
        const int ih = rw + dh;
        const bool vh = (ih < 32);
        for (int kwi = 0; kwi < nw; ++kwi) {
            const int kw = pw ? kwi * 2 : 1;
            const int dw = pw ? (1 - kwi) : 0;  // iw = c + dw
            const int iw = c + dw;
            const bool valid = vh && (iw < 32);
            const int tap = kh * 3 + kw;
            const __hip_bfloat16* abase = xbase + ih * 512 + iw * 16 + offq;
            const __hip_bfloat16* bbase = wt + tap * 16384 + wlane;
            #pragma unroll
            for (int s = 0; s < 4; ++s) {
                bf16x8 afrag = *(const bf16x8*)(abase + s * 32768);
                if (!valid) afrag = zf;
                #pragma unroll
                for (int t = 0; t < 8; ++t) {
                    bf16x8 bfrag = *(const bf16x8*)(bbase + t * 2048 + s * 32);
                    acc[t] = __builtin_amdgcn_mfma_f32_16x16x32_bf16(
                        afrag, bfrag, acc[t], 0, 0, 0);
                }
            }
        }
    }

    // Epilogue: +bias, squash over d (16 lanes of each quad), store.
    // C/D layout: col(n=d) = lane&15, row(m=pixel) = quad*4 + reg.
    const int oh = rw * 2 + ph;
    #pragma unroll
    for (int t = 0; t < 8; ++t) {
        const float bb = bias[t * 16 + n16];
        f32x4 v = acc[t];
        #pragma unroll
        for (int r = 0; r < 4; ++r) {
            float y = v[r] + bb;
            float sq = y * y;
            sq += __shfl_xor(sq, 1, 64);
            sq += __shfl_xor(sq, 2, 64);
            sq += __shfl_xor(sq, 4, 64);
            sq += __shfl_xor(sq, 8, 64);
            const float f = sq / ((1.f + sq) * sqrtf(sq + 1e-7f));
            const int p  = quad * 4 + r;                 // pixel row in tile
            const int ow = (ch * 16 + p) * 2 + pw;
            out[(((b * 8 + t) * 64 + oh) * 64 + ow) * 16 + n16] = y * f;
        }
    }
}

extern "C" void kernel_launch(void* const* d_in, const int* in_sizes, int n_in,
                              void* d_out, int out_size, void* d_ws, size_t ws_size,
                              hipStream_t stream) {
    const float* x    = (const float*)d_in[0];
    const float* wgt  = (const float*)d_in[1];
    const float* bias = (const float*)d_in[2];
    float* out = (float*)d_out;

    __hip_bfloat16* xbf = (__hip_bfloat16*)d_ws;
    __hip_bfloat16* wtb = xbf + XBF_ELEMS;

    convert_x<<<XBF_ELEMS / (256 * 8), 256, 0, stream>>>(x, xbf);
    transpose_w<<<(9 * 128 * 128) / 256, 256, 0, stream>>>(wgt, wtb);

    dim3 grid(16, 4, 16);  // (row-pair, parity-class, batch)
    caps_mfma<<<grid, 256, 0, stream>>>(xbf, wtb, bias, out);
}

// Round 3
// 102.333 us; speedup vs baseline: 1.5350x; 1.3824x over previous
//
#include <hip/hip_runtime.h>
#include <hip/hip_bf16.h>
#include <math.h>

// out = squash(ConvTranspose2d(x)+bias); routing loop is identity (R0 analysis).
// GEMM per parity class (ph,pw): out[px,co] = bias + sum_{tap in class} X·W_tap
// bf16 MFMA 16x16x32. Per-class taps: (0,0)->1, (0,1)/(1,0)->2, (1,1)->4.
//
// ws: Wl bf16, fragment-linear [9][4][8][64][8] (tap, s, t, lane, j) = 288 KB.
//     B-frag def: B[n=lane&15][k=quad*8+j], co = t*16+n, ci = s*32+quad*8+j.

typedef __attribute__((ext_vector_type(8))) __bf16 bf16x8;
typedef __attribute__((ext_vector_type(4))) float f32x4;

__global__ __launch_bounds__(256) void make_wfrag(const float* __restrict__ w,
                                                  __hip_bfloat16* __restrict__ wl) {
    const int idx = blockIdx.x * 256 + threadIdx.x;  // = ci*1152 + co*9 + tap (coalesced read)
    const int ci  = idx / 1152;
    const int rem = idx - ci * 1152;
    const int co  = rem / 9;
    const int tap = rem - co * 9;
    const int s = ci >> 5, quad = (ci >> 3) & 3, j = ci & 7;
    const int t = co >> 4, n16 = co & 15;
    const int dst = ((((tap * 4 + s) * 8 + t) * 64) + quad * 16 + n16) * 8 + j;
    wl[dst] = __float2bfloat16(w[idx]);
}

template <int PH, int PW>
__device__ __forceinline__ void caps_body(
    const float* __restrict__ x, const __hip_bfloat16* __restrict__ wl,
    const float* __restrict__ bias, float* __restrict__ out)
{
    const int tid = threadIdx.x, lane = tid & 63, wv = tid >> 6;
    const int q = blockIdx.x, b = blockIdx.z;
    const int rw   = q * 2 + (wv >> 1);   // class row (oh = 2*rw + PH)
    const int ch   = wv & 1;              // column half
    const int n16  = lane & 15;
    const int quad = lane >> 4;
    const int c    = ch * 16 + n16;       // class col (ow = 2*c + PW)

    float bb[8];
    #pragma unroll
    for (int t = 0; t < 8; ++t) bb[t] = bias[t * 16 + n16];

    // A-frag: A[m=n16][k=quad*8+j] -> x[b, mi=2s+(quad>>1), ih, iw, (quad&1)*8 + j] (f32)
    const float* xb = x + b * 131072 + (quad >> 1) * 16384 + (quad & 1) * 8;

    f32x4 acc[8];
    #pragma unroll
    for (int t = 0; t < 8; ++t) acc[t] = (f32x4){0.f, 0.f, 0.f, 0.f};

    #pragma unroll
    for (int khi = 0; khi < (PH ? 2 : 1); ++khi) {
        const int kh = PH ? khi * 2 : 1;
        const int dh = PH ? (1 - khi) : 0;
        const int ih = rw + dh;
        const bool vh = (ih < 32);
        const int ihc = vh ? ih : 31;
        #pragma unroll
        for (int kwi = 0; kwi < (PW ? 2 : 1); ++kwi) {
            const int kw = PW ? kwi * 2 : 1;
            const int dw = PW ? (1 - kwi) : 0;
            const int iw = c + dw;
            const bool valid = vh && (iw < 32);
            const int iwc = (iw < 32) ? iw : 31;
            const int tap = kh * 3 + kw;
            const float* ab = xb + ihc * 512 + iwc * 16;
            const __hip_bfloat16* wb = wl + tap * 16384 + lane * 8;
            #pragma unroll
            for (int s = 0; s < 4; ++s) {
                float4 lo = *(const float4*)(ab + s * 32768);
                float4 hi = *(const float4*)(ab + s * 32768 + 4);
                union { bf16x8 v; __hip_bfloat162 h[4]; } ua;
                ua.h[0] = __float22bfloat162_rn(make_float2(lo.x, lo.y));
                ua.h[1] = __float22bfloat162_rn(make_float2(lo.z, lo.w));
                ua.h[2] = __float22bfloat162_rn(make_float2(hi.x, hi.y));
                ua.h[3] = __float22bfloat162_rn(make_float2(hi.z, hi.w));
                const bf16x8 afrag = valid ? ua.v : (bf16x8){};
                #pragma unroll
                for (int t = 0; t < 8; ++t) {
                    bf16x8 bfrag = *(const bf16x8*)(wb + (s * 8 + t) * 512);
                    acc[t] = __builtin_amdgcn_mfma_f32_16x16x32_bf16(
                        afrag, bfrag, acc[t], 0, 0, 0);
                }
            }
        }
    }

    // Epilogue: +bias, squash over d (16 lanes of each quad), nontemporal store.
    // C/D layout: d = n16, pixel row p = quad*4 + reg.
    const int oh = rw * 2 + PH;
    #pragma unroll
    for (int half = 0; half < 2; ++half) {
        float y[4][4], sq[4][4];
        #pragma unroll
        for (int tt = 0; tt < 4; ++tt) {
            const int t = half * 4 + tt;
            #pragma unroll
            for (int r = 0; r < 4; ++r) {
                y[tt][r]  = acc[t][r] + bb[t];
                sq[tt][r] = y[tt][r] * y[tt][r];
            }
        }
        #pragma unroll
        for (int st = 1; st <= 8; st <<= 1) {
            #pragma unroll
            for (int tt = 0; tt < 4; ++tt)
                #pragma unroll
                for (int r = 0; r < 4; ++r)
                    sq[tt][r] += __shfl_xor(sq[tt][r], st, 64);
        }
        #pragma unroll
        for (int tt = 0; tt < 4; ++tt) {
            const int t = half * 4 + tt;
            #pragma unroll
            for (int r = 0; r < 4; ++r) {
                const float s2 = sq[tt][r];
                const float f  = s2 / ((1.f + s2) * sqrtf(s2 + 1e-7f));
                const int p  = quad * 4 + r;
                const int ow = (ch * 16 + p) * 2 + PW;
                __builtin_nontemporal_store(
                    y[tt][r] * f,
                    out + (((b * 8 + t) * 64 + oh) * 64 + ow) * 16 + n16);
            }
        }
    }
}

__global__ __launch_bounds__(256, 4) void caps_mfma(
    const float* __restrict__ x, const __hip_bfloat16* __restrict__ wl,
    const float* __restrict__ bias, float* __restrict__ out)
{
    switch (blockIdx.y) {  // uniform per block: ph = pc>>1, pw = pc&1
    case 0:  caps_body<0, 0>(x, wl, bias, out); break;
    case 1:  caps_body<0, 1>(x, wl, bias, out); break;
    case 2:  caps_body<1, 0>(x, wl, bias, out); break;
    default: caps_body<1, 1>(x, wl, bias, out); break;
    }
}

extern "C" void kernel_launch(void* const* d_in, const int* in_sizes, int n_in,
                              void* d_out, int out_size, void* d_ws, size_t ws_size,
                              hipStream_t stream) {
    const float* x    = (const float*)d_in[0];
    const float* wgt  = (const float*)d_in[1];
    const float* bias = (const float*)d_in[2];
    float* out = (float*)d_out;
    __hip_bfloat16* wlb = (__hip_bfloat16*)d_ws;

    make_wfrag<<<576, 256, 0, stream>>>(wgt, wlb);          // 147456 elems
    caps_mfma<<<dim3(16, 4, 16), 256, 0, stream>>>(x, wlb, bias, out);
}

// Round 4
// 98.702 us; speedup vs baseline: 1.5914x; 1.0368x over previous
//
#include <hip/hip_runtime.h>
#include <hip/hip_bf16.h>
#include <math.h>

// out = squash(ConvTranspose2d(x)+bias); routing loop is identity (R0 analysis).
// GEMM per parity class (ph,pw): out[px,co] = bias + sum_{tap in class} X·W_tap
// bf16 MFMA 16x16x32. Class taps: (0,0)->1, (0,1)/(1,0)->2, (1,1)->4.
//
// R4: xbf precompute (A-frag = 1 dwordx4), 2 M-tiles (row-pair) per wave so
// every B-frag is reused 2x, class on blockIdx.x for dispatch balance,
// prep kernels fused into one launch.
//
// ws: [0,4MB)   xbf bf16 [16][8][32][32][16] (x strides /2B)
//     [4MB,..)  Wl  bf16 [9][4][8][64][8] (tap,s,t,lane,j); B[n=lane&15][k=quad*8+j],
//               co = t*16+n, ci = s*32+quad*8+j.

typedef __attribute__((ext_vector_type(8))) __bf16 bf16x8;
typedef __attribute__((ext_vector_type(4))) float f32x4;

#define XBF_ELEMS (16 * 8 * 32 * 32 * 16)  // 2097152

__global__ __launch_bounds__(256) void prep(const float* __restrict__ x,
                                            const float* __restrict__ w,
                                            __hip_bfloat16* __restrict__ xbf,
                                            __hip_bfloat16* __restrict__ wl) {
    const int bx = blockIdx.x;
    if (bx < 1024) {  // x -> bf16, 8 elems/thread
        const int i = (bx * 256 + threadIdx.x) * 8;
        float4 a = *(const float4*)(x + i);
        float4 b = *(const float4*)(x + i + 4);
        union { bf16x8 v; __hip_bfloat162 h[4]; } u;
        u.h[0] = __float22bfloat162_rn(make_float2(a.x, a.y));
        u.h[1] = __float22bfloat162_rn(make_float2(a.z, a.w));
        u.h[2] = __float22bfloat162_rn(make_float2(b.x, b.y));
        u.h[3] = __float22bfloat162_rn(make_float2(b.z, b.w));
        *(bf16x8*)(xbf + i) = u.v;
    } else {          // w -> fragment-linear bf16
        const int idx = (bx - 1024) * 256 + threadIdx.x;  // = ci*1152+co*9+tap
        const int ci  = idx / 1152;
        const int rem = idx - ci * 1152;
        const int co  = rem / 9;
        const int tap = rem - co * 9;
        const int s = ci >> 5, quad = (ci >> 3) & 3, j = ci & 7;
        const int t = co >> 4, n16 = co & 15;
        const int dst = ((((tap * 4 + s) * 8 + t) * 64) + quad * 16 + n16) * 8 + j;
        wl[dst] = __float2bfloat16(w[idx]);
    }
}

template <int PH, int PW>
__device__ __forceinline__ void caps_body(
    const __hip_bfloat16* __restrict__ xbf, const __hip_bfloat16* __restrict__ wl,
    const float* __restrict__ bias, float* __restrict__ out)
{
    const int tid = threadIdx.x, lane = tid & 63, wv = tid >> 6;
    const int q = blockIdx.y, b = blockIdx.z;
    const int rp = wv >> 1, ch = wv & 1;
    const int rw0 = q * 4 + rp * 2;       // class rows rw0, rw0+1 (oh = 2*rw+PH)
    const int n16  = lane & 15;
    const int quad = lane >> 4;
    const int c    = ch * 16 + n16;       // class col (ow = 2*c + PW)

    float bb[8];
    #pragma unroll
    for (int t = 0; t < 8; ++t) bb[t] = bias[t * 16 + n16];

    // A-frag: A[m=n16][k=quad*8+j] = xbf[b, 2s+(quad>>1), ih, iw, (quad&1)*8+j]
    const __hip_bfloat16* xq = xbf + b * 131072 + (quad >> 1) * 16384 + (quad & 1) * 8;
    const __hip_bfloat16* wq = wl + lane * 8;

    f32x4 acc[2][8];
    #pragma unroll
    for (int r = 0; r < 2; ++r)
        #pragma unroll
        for (int t = 0; t < 8; ++t) acc[r][t] = (f32x4){0.f, 0.f, 0.f, 0.f};

    #pragma unroll
    for (int khi = 0; khi < (PH ? 2 : 1); ++khi) {
        const int kh = PH ? khi * 2 : 1;
        const int dh = PH ? (1 - khi) : 0;
        const int ih0 = rw0 + dh, ih1 = ih0 + 1;
        const bool v0 = (ih0 < 32), v1 = (ih1 < 32);      // wave-uniform
        const int ih0c = v0 ? ih0 : 31, ih1c = v1 ? ih1 : 31;
        #pragma unroll
        for (int kwi = 0; kwi < (PW ? 2 : 1); ++kwi) {
            const int kw = PW ? kwi * 2 : 1;
            const int dw = PW ? (1 - kwi) : 0;
            const int iw = c + dw;
            const bool vw = (iw < 32);                    // per-lane
            const int iwc = vw ? iw : 31;
            const int tap = kh * 3 + kw;
            const __hip_bfloat16* a0p = xq + ih0c * 512 + iwc * 16;
            const __hip_bfloat16* a1p = xq + ih1c * 512 + iwc * 16;
            const __hip_bfloat16* wb  = wq + tap * 16384;
            #pragma unroll
            for (int s = 0; s < 4; ++s) {
                bf16x8 a0 = *(const bf16x8*)(a0p + s * 32768);
                bf16x8 a1 = *(const bf16x8*)(a1p + s * 32768);
                if (!(v0 && vw)) a0 = (bf16x8){};
                if (!(v1 && vw)) a1 = (bf16x8){};
                #pragma unroll
                for (int t = 0; t < 8; ++t) {
                    bf16x8 bf = *(const bf16x8*)(wb + (s * 8 + t) * 512);
                    acc[0][t] = __builtin_amdgcn_mfma_f32_16x16x32_bf16(a0, bf, acc[0][t], 0, 0, 0);
                    acc[1][t] = __builtin_amdgcn_mfma_f32_16x16x32_bf16(a1, bf, acc[1][t], 0, 0, 0);
                }
            }
        }
    }

    // Epilogue: +bias, squash over d (16 lanes of each quad), nontemporal store.
    // C/D: d = n16, pixel row p = quad*4 + reg -> ow = 2*(ch*16+p) + PW.
    #pragma unroll
    for (int row = 0; row < 2; ++row) {
        const int oh = (rw0 + row) * 2 + PH;
        #pragma unroll
        for (int half = 0; half < 2; ++half) {
            float y[4][4], sq[4][4];
            #pragma unroll
            for (int tt = 0; tt < 4; ++tt)
                #pragma unroll
                for (int r = 0; r < 4; ++r) {
                    y[tt][r]  = acc[row][half * 4 + tt][r] + bb[half * 4 + tt];
                    sq[tt][r] = y[tt][r] * y[tt][r];
                }
            #pragma unroll
            for (int st = 1; st <= 8; st <<= 1)
                #pragma unroll
                for (int tt = 0; tt < 4; ++tt)
                    #pragma unroll
                    for (int r = 0; r < 4; ++r)
                        sq[tt][r] += __shfl_xor(sq[tt][r], st, 64);
            #pragma unroll
            for (int tt = 0; tt < 4; ++tt)
                #pragma unroll
                for (int r = 0; r < 4; ++r) {
                    const float s2 = sq[tt][r];
                    const float f  = s2 / ((1.f + s2) * sqrtf(s2 + 1e-7f));
                    const int ow = (ch * 16 + quad * 4 + r) * 2 + PW;
                    __builtin_nontemporal_store(
                        y[tt][r] * f,
                        out + (((b * 8 + half * 4 + tt) * 64 + oh) * 64 + ow) * 16 + n16);
                }
        }
    }
}

__global__ __launch_bounds__(256, 2) void caps_mfma(
    const __hip_bfloat16* __restrict__ xbf, const __hip_bfloat16* __restrict__ wl,
    const float* __restrict__ bias, float* __restrict__ out)
{
    switch (blockIdx.x) {  // class on x: consecutive blocks interleave classes
    case 0:  caps_body<0, 0>(xbf, wl, bias, out); break;
    case 1:  caps_body<0, 1>(xbf, wl, bias, out); break;
    case 2:  caps_body<1, 0>(xbf, wl, bias, out); break;
    default: caps_body<1, 1>(xbf, wl, bias, out); break;
    }
}

extern "C" void kernel_launch(void* const* d_in, const int* in_sizes, int n_in,
                              void* d_out, int out_size, void* d_ws, size_t ws_size,
                              hipStream_t stream) {
    const float* x    = (const float*)d_in[0];
    const float* wgt  = (const float*)d_in[1];
    const float* bias = (const float*)d_in[2];
    float* out = (float*)d_out;

    __hip_bfloat16* xbf = (__hip_bfloat16*)d_ws;
    __hip_bfloat16* wlb = xbf + XBF_ELEMS;

    prep<<<1024 + 576, 256, 0, stream>>>(x, wgt, xbf, wlb);
    caps_mfma<<<dim3(4, 8, 16), 256, 0, stream>>>(xbf, wlb, bias, out);
}

// Round 5
// 94.663 us; speedup vs baseline: 1.6593x; 1.0427x over previous
//
#include <hip/hip_runtime.h>
#include <hip/hip_bf16.h>
#include <math.h>

// out = squash(ConvTranspose2d(x)+bias); routing loop is identity (R0 analysis).
// GEMM per parity class (ph,pw): out[px,co] = bias + sum_{tap in class} X·W_tap
// bf16 MFMA 16x16x32. Class taps: (0,0)->1, (0,1)/(1,0)->2, (1,1)->4.
//
// R5: co split across blocks (4 co-tiles/block) -> 1024 blocks = 4 blocks/CU,
// 4 waves/SIMD (50% occ) to hide L2 latency; acc 32 VGPR; launch_bounds(256,4).
//
// ws: [0,4MB)   xbf bf16 [16][8][32][32][16] (x strides /2B)
//     [4MB,..)  Wl  bf16 [9][4][8][64][8] (tap,s,t,lane,j); B[n=lane&15][k=quad*8+j],
//               co = t*16+n, ci = s*32+quad*8+j.

typedef __attribute__((ext_vector_type(8))) __bf16 bf16x8;
typedef __attribute__((ext_vector_type(4))) float f32x4;

#define XBF_ELEMS (16 * 8 * 32 * 32 * 16)  // 2097152

__global__ __launch_bounds__(256) void prep(const float* __restrict__ x,
                                            const float* __restrict__ w,
                                            __hip_bfloat16* __restrict__ xbf,
                                            __hip_bfloat16* __restrict__ wl) {
    const int bx = blockIdx.x;
    if (bx < 1024) {  // x -> bf16, 8 elems/thread
        const int i = (bx * 256 + threadIdx.x) * 8;
        float4 a = *(const float4*)(x + i);
        float4 b = *(const float4*)(x + i + 4);
        union { bf16x8 v; __hip_bfloat162 h[4]; } u;
        u.h[0] = __float22bfloat162_rn(make_float2(a.x, a.y));
        u.h[1] = __float22bfloat162_rn(make_float2(a.z, a.w));
        u.h[2] = __float22bfloat162_rn(make_float2(b.x, b.y));
        u.h[3] = __float22bfloat162_rn(make_float2(b.z, b.w));
        *(bf16x8*)(xbf + i) = u.v;
    } else {          // w -> fragment-linear bf16
        const int idx = (bx - 1024) * 256 + threadIdx.x;  // = ci*1152+co*9+tap
        const int ci  = idx / 1152;
        const int rem = idx - ci * 1152;
        const int co  = rem / 9;
        const int tap = rem - co * 9;
        const int s = ci >> 5, quad = (ci >> 3) & 3, j = ci & 7;
        const int t = co >> 4, n16 = co & 15;
        const int dst = ((((tap * 4 + s) * 8 + t) * 64) + quad * 16 + n16) * 8 + j;
        wl[dst] = __float2bfloat16(w[idx]);
    }
}

template <int PH, int PW>
__device__ __forceinline__ void caps_body(
    const __hip_bfloat16* __restrict__ xbf, const __hip_bfloat16* __restrict__ wl,
    const float* __restrict__ bias, float* __restrict__ out, int nh)
{
    const int tid = threadIdx.x, lane = tid & 63, wv = tid >> 6;
    const int q = blockIdx.y, b = blockIdx.z;
    const int rp = wv >> 1, ch = wv & 1;
    const int rw0 = q * 4 + rp * 2;       // class rows rw0, rw0+1 (oh = 2*rw+PH)
    const int n16  = lane & 15;
    const int quad = lane >> 4;
    const int c    = ch * 16 + n16;       // class col (ow = 2*c + PW)

    float bb[4];
    #pragma unroll
    for (int tt = 0; tt < 4; ++tt) bb[tt] = bias[(nh * 4 + tt) * 16 + n16];

    // A-frag: A[m=n16][k=quad*8+j] = xbf[b, 2s+(quad>>1), ih, iw, (quad&1)*8+j]
    const __hip_bfloat16* xq = xbf + b * 131072 + (quad >> 1) * 16384 + (quad & 1) * 8;
    const __hip_bfloat16* wq = wl + lane * 8 + (nh * 4) * 512;  // co-half base

    f32x4 acc[2][4];
    #pragma unroll
    for (int r = 0; r < 2; ++r)
        #pragma unroll
        for (int tt = 0; tt < 4; ++tt) acc[r][tt] = (f32x4){0.f, 0.f, 0.f, 0.f};

    #pragma unroll
    for (int khi = 0; khi < (PH ? 2 : 1); ++khi) {
        const int kh = PH ? khi * 2 : 1;
        const int dh = PH ? (1 - khi) : 0;
        const int ih0 = rw0 + dh, ih1 = ih0 + 1;
        const bool v0 = (ih0 < 32), v1 = (ih1 < 32);      // wave-uniform
        const int ih0c = v0 ? ih0 : 31, ih1c = v1 ? ih1 : 31;
        #pragma unroll
        for (int kwi = 0; kwi < (PW ? 2 : 1); ++kwi) {
            const int kw = PW ? kwi * 2 : 1;
            const int dw = PW ? (1 - kwi) : 0;
            const int iw = c + dw;
            const bool vw = (iw < 32);                    // per-lane
            const int iwc = vw ? iw : 31;
            const int tap = kh * 3 + kw;
            const __hip_bfloat16* a0p = xq + ih0c * 512 + iwc * 16;
            const __hip_bfloat16* a1p = xq + ih1c * 512 + iwc * 16;
            const __hip_bfloat16* wb  = wq + tap * 16384;
            #pragma unroll
            for (int s = 0; s < 4; ++s) {
                bf16x8 a0 = *(const bf16x8*)(a0p + s * 32768);
                bf16x8 a1 = *(const bf16x8*)(a1p + s * 32768);
                if (!(v0 && vw)) a0 = (bf16x8){};
                if (!(v1 && vw)) a1 = (bf16x8){};
                #pragma unroll
                for (int tt = 0; tt < 4; ++tt) {
                    bf16x8 bf = *(const bf16x8*)(wb + (s * 8 + tt) * 512);
                    acc[0][tt] = __builtin_amdgcn_mfma_f32_16x16x32_bf16(a0, bf, acc[0][tt], 0, 0, 0);
                    acc[1][tt] = __builtin_amdgcn_mfma_f32_16x16x32_bf16(a1, bf, acc[1][tt], 0, 0, 0);
                }
            }
        }
    }

    // Epilogue: +bias, squash over d (16 lanes of each quad), nontemporal store.
    // C/D: d = n16, pixel row p = quad*4 + reg -> ow = 2*(ch*16+p) + PW.
    #pragma unroll
    for (int row = 0; row < 2; ++row) {
        const int oh = (rw0 + row) * 2 + PH;
        float y[4][4], sq[4][4];
        #pragma unroll
        for (int tt = 0; tt < 4; ++tt)
            #pragma unroll
            for (int r = 0; r < 4; ++r) {
                y[tt][r]  = acc[row][tt][r] + bb[tt];
                sq[tt][r] = y[tt][r] * y[tt][r];
            }
        #pragma unroll
        for (int st = 1; st <= 8; st <<= 1)
            #pragma unroll
            for (int tt = 0; tt < 4; ++tt)
                #pragma unroll
                for (int r = 0; r < 4; ++r)
                    sq[tt][r] += __shfl_xor(sq[tt][r], st, 64);
        #pragma unroll
        for (int tt = 0; tt < 4; ++tt)
            #pragma unroll
            for (int r = 0; r < 4; ++r) {
                const float s2 = sq[tt][r];
                const float f  = s2 / ((1.f + s2) * sqrtf(s2 + 1e-7f));
                const int ow = (ch * 16 + quad * 4 + r) * 2 + PW;
                __builtin_nontemporal_store(
                    y[tt][r] * f,
                    out + (((b * 8 + nh * 4 + tt) * 64 + oh) * 64 + ow) * 16 + n16);
            }
    }
}

__global__ __launch_bounds__(256, 4) void caps_mfma(
    const __hip_bfloat16* __restrict__ xbf, const __hip_bfloat16* __restrict__ wl,
    const float* __restrict__ bias, float* __restrict__ out)
{
    const int nh = blockIdx.x >> 2;      // co-half 0/1
    switch (blockIdx.x & 3) {            // class fastest-varying for balance
    case 0:  caps_body<0, 0>(xbf, wl, bias, out, nh); break;
    case 1:  caps_body<0, 1>(xbf, wl, bias, out, nh); break;
    case 2:  caps_body<1, 0>(xbf, wl, bias, out, nh); break;
    default: caps_body<1, 1>(xbf, wl, bias, out, nh); break;
    }
}

extern "C" void kernel_launch(void* const* d_in, const int* in_sizes, int n_in,
                              void* d_out, int out_size, void* d_ws, size_t ws_size,
                              hipStream_t stream) {
    const float* x    = (const float*)d_in[0];
    const float* wgt  = (const float*)d_in[1];
    const float* bias = (const float*)d_in[2];
    float* out = (float*)d_out;

    __hip_bfloat16* xbf = (__hip_bfloat16*)d_ws;
    __hip_bfloat16* wlb = xbf + XBF_ELEMS;

    prep<<<1024 + 576, 256, 0, stream>>>(x, wgt, xbf, wlb);
    caps_mfma<<<dim3(8, 8, 16), 256, 0, stream>>>(xbf, wlb, bias, out);
}